// Round 1
// baseline (31143.149 us; speedup 1.0000x reference)
//
#include <hip/hip_runtime.h>
#include <hip/hip_fp16.h>

// GRU 2-layer, B=256 S=1024 F=75 H=256.
// Round 1: batch-parallel baseline. 128 blocks x 256 threads, 2 batch rows/block.
// Weights converted to __half2 (c-pair interleaved, gate-major transposed) in d_ws.
// Dots via v_dot2_f32_f16; state kept fp32; h/x quantized to f16 only as dot operands.

#define NB 256
#define NS 1024
#define NF 75
#define NH 256
#define NG 768   // 3*NH

// half2-element offsets inside d_ws
#define W0H_OFF 0        // w_hh0^T paired: [128][768]
#define W1I_OFF 98304    // w_ih1^T paired: [128][768]
#define W1H_OFF 196608   // w_hh1^T paired: [128][768]
#define W0I_OFF 294912   // w_ih0^T paired: [38][768] (c=75 padded with 0)
#define WT_TOTAL 324096  // total half2 elements (=1,296,384 bytes)

typedef _Float16 half2_raw __attribute__((ext_vector_type(2)));

__device__ __forceinline__ float fdot2f(__half2 a, __half2 b, float c) {
#if __has_builtin(__builtin_amdgcn_fdot2)
  return __builtin_amdgcn_fdot2(__builtin_bit_cast(half2_raw, a),
                                __builtin_bit_cast(half2_raw, b), c, false);
#else
  return c + __half2float(a.x) * __half2float(b.x) +
             __half2float(a.y) * __half2float(b.y);
#endif
}

__global__ void prep_weights(const float* __restrict__ wih0,
                             const float* __restrict__ whh0,
                             const float* __restrict__ wih1,
                             const float* __restrict__ whh1,
                             __half2* __restrict__ wt) {
  const int stride = gridDim.x * blockDim.x;
  for (int i = blockIdx.x * blockDim.x + threadIdx.x; i < WT_TOTAL; i += stride) {
    if (i < 3 * 98304) {
      const int m = i / 98304;               // 0:whh0 1:wih1 2:whh1
      const int r = i - m * 98304;
      const int c2 = r / NG, j = r - c2 * NG;
      const float* src = (m == 0) ? whh0 : (m == 1) ? wih1 : whh1;
      wt[i] = __floats2half2_rn(src[j * NH + 2 * c2], src[j * NH + 2 * c2 + 1]);
    } else {
      const int r = i - 3 * 98304;
      const int c2 = r / NG, j = r - c2 * NG;
      const float a = wih0[j * NF + 2 * c2];
      const float b = (2 * c2 + 1 < NF) ? wih0[j * NF + 2 * c2 + 1] : 0.f;
      wt[i] = __floats2half2_rn(a, b);
    }
  }
}

__global__ __launch_bounds__(256) void gru_seq(
    const float* __restrict__ x,
    const float* __restrict__ b_ih0, const float* __restrict__ b_hh0,
    const float* __restrict__ b_ih1, const float* __restrict__ b_hh1,
    const float* __restrict__ w_lin, const float* __restrict__ b_lin,
    const __half2* __restrict__ wt,
    float* __restrict__ out)
{
  const int k = threadIdx.x;              // hidden unit
  const int r0 = blockIdx.x * 2;          // first of two batch rows

  __shared__ __half h0h[2][NH];
  __shared__ __half h1h[2][NH];
  __shared__ __half xsh[2][NF + 1];       // elem 75 = zero pad
  __shared__ float  red[256];

  const __half2* __restrict__ w0h = wt + W0H_OFF;
  const __half2* __restrict__ w1i = wt + W1I_OFF;
  const __half2* __restrict__ w1h = wt + W1H_OFF;
  const __half2* __restrict__ w0i = wt + W0I_OFF;

  const float cbr0 = b_ih0[k]          + b_hh0[k];
  const float cbz0 = b_ih0[NH + k]     + b_hh0[NH + k];
  const float bnx0 = b_ih0[2 * NH + k];
  const float bnh0 = b_hh0[2 * NH + k];
  const float cbr1 = b_ih1[k]          + b_hh1[k];
  const float cbz1 = b_ih1[NH + k]     + b_hh1[NH + k];
  const float bnx1 = b_ih1[2 * NH + k];
  const float bnh1 = b_hh1[2 * NH + k];

  float h0f[2] = {0.f, 0.f};
  float h1f[2] = {0.f, 0.f};
  h0h[0][k] = __float2half(0.f);
  h0h[1][k] = __float2half(0.f);
  h1h[0][k] = __float2half(0.f);
  h1h[1][k] = __float2half(0.f);
  if (k < 2) xsh[k][NF] = __float2half(0.f);   // permanent pad

  const float* __restrict__ xr = x + (size_t)r0 * NS * NF;
  const bool xactive = (k < 2 * NF);
  const int  xrow = (k < NF) ? 0 : 1;
  const int  xcol = (k < NF) ? k : k - NF;
  float xpre = 0.f;
  if (xactive) xpre = xr[(size_t)xrow * NS * NF + xcol];

  for (int t = 0; t < NS; ++t) {
    if (xactive) xsh[xrow][xcol] = __float2half(xpre);
    __syncthreads();                                   // S1: xs + prev h1 visible
    if (xactive && (t + 1 < NS))
      xpre = xr[(size_t)xrow * NS * NF + (size_t)(t + 1) * NF + xcol];

    // ------------- layer 0 -------------
    float ar[2]  = {cbr0, cbr0}, az[2]  = {cbz0, cbz0};
    float anx[2] = {bnx0, bnx0}, anh[2] = {bnh0, bnh0};

    #pragma unroll 2
    for (int c2 = 0; c2 < 38; ++c2) {
      const __half2 wr = w0i[c2 * NG + k];
      const __half2 wz = w0i[c2 * NG + NH + k];
      const __half2 wn = w0i[c2 * NG + 2 * NH + k];
      const __half2 xa = *(const __half2*)&xsh[0][2 * c2];
      const __half2 xb = *(const __half2*)&xsh[1][2 * c2];
      ar[0]  = fdot2f(wr, xa, ar[0]);   ar[1]  = fdot2f(wr, xb, ar[1]);
      az[0]  = fdot2f(wz, xa, az[0]);   az[1]  = fdot2f(wz, xb, az[1]);
      anx[0] = fdot2f(wn, xa, anx[0]);  anx[1] = fdot2f(wn, xb, anx[1]);
    }
    #pragma unroll 2
    for (int c2 = 0; c2 < 128; ++c2) {
      const __half2 wr = w0h[c2 * NG + k];
      const __half2 wz = w0h[c2 * NG + NH + k];
      const __half2 wn = w0h[c2 * NG + 2 * NH + k];
      const __half2 ha = *(const __half2*)&h0h[0][2 * c2];
      const __half2 hb = *(const __half2*)&h0h[1][2 * c2];
      ar[0]  = fdot2f(wr, ha, ar[0]);   ar[1]  = fdot2f(wr, hb, ar[1]);
      az[0]  = fdot2f(wz, ha, az[0]);   az[1]  = fdot2f(wz, hb, az[1]);
      anh[0] = fdot2f(wn, ha, anh[0]);  anh[1] = fdot2f(wn, hb, anh[1]);
    }
    #pragma unroll
    for (int rr = 0; rr < 2; ++rr) {
      const float r = 1.f / (1.f + __expf(-ar[rr]));
      const float z = 1.f / (1.f + __expf(-az[rr]));
      const float n = tanhf(anx[rr] + r * anh[rr]);
      h0f[rr] = (1.f - z) * n + z * h0f[rr];
    }
    __syncthreads();                                   // S2: all reads of h0h done
    h0h[0][k] = __float2half(h0f[0]);
    h0h[1][k] = __float2half(h0f[1]);
    __syncthreads();                                   // S3: new h0h visible

    // ------------- layer 1 -------------
    ar[0]  = cbr1; ar[1]  = cbr1;  az[0]  = cbz1; az[1]  = cbz1;
    anx[0] = bnx1; anx[1] = bnx1;  anh[0] = bnh1; anh[1] = bnh1;

    #pragma unroll 2
    for (int c2 = 0; c2 < 128; ++c2) {
      const __half2 wr = w1i[c2 * NG + k];
      const __half2 wz = w1i[c2 * NG + NH + k];
      const __half2 wn = w1i[c2 * NG + 2 * NH + k];
      const __half2 ha = *(const __half2*)&h0h[0][2 * c2];
      const __half2 hb = *(const __half2*)&h0h[1][2 * c2];
      ar[0]  = fdot2f(wr, ha, ar[0]);   ar[1]  = fdot2f(wr, hb, ar[1]);
      az[0]  = fdot2f(wz, ha, az[0]);   az[1]  = fdot2f(wz, hb, az[1]);
      anx[0] = fdot2f(wn, ha, anx[0]);  anx[1] = fdot2f(wn, hb, anx[1]);
    }
    #pragma unroll 2
    for (int c2 = 0; c2 < 128; ++c2) {
      const __half2 wr = w1h[c2 * NG + k];
      const __half2 wz = w1h[c2 * NG + NH + k];
      const __half2 wn = w1h[c2 * NG + 2 * NH + k];
      const __half2 ha = *(const __half2*)&h1h[0][2 * c2];
      const __half2 hb = *(const __half2*)&h1h[1][2 * c2];
      ar[0]  = fdot2f(wr, ha, ar[0]);   ar[1]  = fdot2f(wr, hb, ar[1]);
      az[0]  = fdot2f(wz, ha, az[0]);   az[1]  = fdot2f(wz, hb, az[1]);
      anh[0] = fdot2f(wn, ha, anh[0]);  anh[1] = fdot2f(wn, hb, anh[1]);
    }
    #pragma unroll
    for (int rr = 0; rr < 2; ++rr) {
      const float r = 1.f / (1.f + __expf(-ar[rr]));
      const float z = 1.f / (1.f + __expf(-az[rr]));
      const float n = tanhf(anx[rr] + r * anh[rr]);
      h1f[rr] = (1.f - z) * n + z * h1f[rr];
    }
    __syncthreads();                                   // S4: all reads of h1h done
    h1h[0][k] = __float2half(h1f[0]);
    h1h[1][k] = __float2half(h1f[1]);
    // loop top's S1 publishes h1h for next iteration
  }

  // ------------- final linear -------------
  const float wl = w_lin[k];
  red[k] = h1f[0] * wl;
  __syncthreads();
  for (int s = 128; s > 0; s >>= 1) {
    if (k < s) red[k] += red[k + s];
    __syncthreads();
  }
  if (k == 0) out[r0] = red[0] + b_lin[0];
  __syncthreads();
  red[k] = h1f[1] * wl;
  __syncthreads();
  for (int s = 128; s > 0; s >>= 1) {
    if (k < s) red[k] += red[k + s];
    __syncthreads();
  }
  if (k == 0) out[r0 + 1] = red[0] + b_lin[0];
}

extern "C" void kernel_launch(void* const* d_in, const int* in_sizes, int n_in,
                              void* d_out, int out_size, void* d_ws, size_t ws_size,
                              hipStream_t stream) {
  (void)in_sizes; (void)n_in; (void)out_size; (void)ws_size;
  const float* x     = (const float*)d_in[0];
  const float* w_ih0 = (const float*)d_in[1];
  const float* w_hh0 = (const float*)d_in[2];
  const float* b_ih0 = (const float*)d_in[3];
  const float* b_hh0 = (const float*)d_in[4];
  const float* w_ih1 = (const float*)d_in[5];
  const float* w_hh1 = (const float*)d_in[6];
  const float* b_ih1 = (const float*)d_in[7];
  const float* b_hh1 = (const float*)d_in[8];
  const float* w_lin = (const float*)d_in[9];
  const float* b_lin = (const float*)d_in[10];

  __half2* wt = (__half2*)d_ws;   // needs 1,296,384 bytes

  prep_weights<<<512, 256, 0, stream>>>(w_ih0, w_hh0, w_ih1, w_hh1, wt);
  gru_seq<<<NB / 2, 256, 0, stream>>>(x, b_ih0, b_hh0, b_ih1, b_hh1,
                                      w_lin, b_lin, wt, (float*)d_out);
}